// Round 1
// baseline (12.655 us; speedup 1.0000x reference)
//
#include <hip/hip_runtime.h>

#define BB 128
#define DD 1024
#define LAMBDA_COEFF 0.005f

// ---------------------------------------------------------------------------
// Kernel 1: per-column mean & rstd (ddof=1) over batch axis for z1 and z2.
// stats layout: [0,D) mean(z1), [D,2D) mean(z2), [2D,3D) rstd(z1), [3D,4D) rstd(z2)
// Block = 256 threads = 64 columns x 4 row-groups; grid = 2*D/64 = 32 blocks.
// ---------------------------------------------------------------------------
__global__ __launch_bounds__(256) void bt_stats(const float* __restrict__ z1,
                                                const float* __restrict__ z2,
                                                float* __restrict__ stats) {
    const int c = threadIdx.x & 63;   // column within block
    const int g = threadIdx.x >> 6;   // row group 0..3
    const int colIdx = blockIdx.x * 64 + c;  // 0..2D-1
    const float* __restrict__ z = (colIdx < DD) ? z1 : z2;
    const int col = (colIdx < DD) ? colIdx : (colIdx - DD);

    float s = 0.f, ss = 0.f;
#pragma unroll
    for (int r = 0; r < 32; ++r) {
        float v = z[(g * 32 + r) * DD + col];
        s += v;
        ss += v * v;
    }

    __shared__ float sh_s[4][64];
    __shared__ float sh_ss[4][64];
    sh_s[g][c] = s;
    sh_ss[g][c] = ss;
    __syncthreads();

    if (g == 0) {
        float S  = sh_s[0][c] + sh_s[1][c] + sh_s[2][c] + sh_s[3][c];
        float SS = sh_ss[0][c] + sh_ss[1][c] + sh_ss[2][c] + sh_ss[3][c];
        float mu  = S * (1.0f / BB);
        float var = (SS - (float)BB * mu * mu) * (1.0f / (BB - 1));
        stats[colIdx]          = mu;
        stats[2 * DD + colIdx] = rsqrtf(var);
    }
}

// ---------------------------------------------------------------------------
// Kernel 2: one block per sample. Closed-form loss from per-row power sums.
// ---------------------------------------------------------------------------
__global__ __launch_bounds__(256) void bt_loss(const float* __restrict__ z1,
                                               const float* __restrict__ z2,
                                               const float* __restrict__ stats,
                                               float* __restrict__ out) {
    const int i   = blockIdx.x;   // sample
    const int tid = threadIdx.x;  // each thread handles 4 consecutive dims

    const float4* __restrict__ z1r = (const float4*)(z1 + i * DD);
    const float4* __restrict__ z2r = (const float4*)(z2 + i * DD);
    const float4* __restrict__ mu1 = (const float4*)(stats);
    const float4* __restrict__ mu2 = (const float4*)(stats + DD);
    const float4* __restrict__ rs1 = (const float4*)(stats + 2 * DD);
    const float4* __restrict__ rs2 = (const float4*)(stats + 3 * DD);

    float4 x1 = z1r[tid], x2 = z2r[tid];
    float4 m1 = mu1[tid], m2 = mu2[tid];
    float4 r1 = rs1[tid], r2 = rs2[tid];

    float a[4] = {(x1.x - m1.x) * r1.x, (x1.y - m1.y) * r1.y,
                  (x1.z - m1.z) * r1.z, (x1.w - m1.w) * r1.w};
    float b[4] = {(x2.x - m2.x) * r2.x, (x2.y - m2.y) * r2.y,
                  (x2.z - m2.z) * r2.z, (x2.w - m2.w) * r2.w};

    __shared__ float sh_ab[2];  // a_i, b_i (the (i,i) normalized entries)

    // per-thread partial power sums
    float vals[7] = {0.f, 0.f, 0.f, 0.f, 0.f, 0.f, 0.f};
    // vals: 0=R1=Σ(d-1)^2  1=A2=Σa^2  2=S1=Σb  3=S2=Σb^2  4=S3=Σb^3  5=S4=Σb^4  6=C2=Σd^2
#pragma unroll
    for (int k = 0; k < 4; ++k) {
        const int d = tid * 4 + k;
        float ak = a[k], bk = b[k];
        float dk = ak * bk;
        float ek = dk - 1.f;
        float b2 = bk * bk;
        vals[0] += ek * ek;
        vals[1] += ak * ak;
        vals[2] += bk;
        vals[3] += b2;
        vals[4] += b2 * bk;
        vals[5] += b2 * b2;
        vals[6] += dk * dk;
        if (d == i) { sh_ab[0] = ak; sh_ab[1] = bk; }
    }

    // wave64 butterfly reduce, then cross-wave via LDS
#pragma unroll
    for (int off = 32; off >= 1; off >>= 1) {
#pragma unroll
        for (int k = 0; k < 7; ++k) vals[k] += __shfl_down(vals[k], off, 64);
    }

    __shared__ float sh_red[4][7];
    const int wave = tid >> 6;
    const int lane = tid & 63;
    if (lane == 0) {
#pragma unroll
        for (int k = 0; k < 7; ++k) sh_red[wave][k] = vals[k];
    }
    __syncthreads();

    if (tid == 0) {
        float R1 = sh_red[0][0] + sh_red[1][0] + sh_red[2][0] + sh_red[3][0];
        float A2 = sh_red[0][1] + sh_red[1][1] + sh_red[2][1] + sh_red[3][1];
        float S1 = sh_red[0][2] + sh_red[1][2] + sh_red[2][2] + sh_red[3][2];
        float S2 = sh_red[0][3] + sh_red[1][3] + sh_red[2][3] + sh_red[3][3];
        float S3 = sh_red[0][4] + sh_red[1][4] + sh_red[2][4] + sh_red[3][4];
        float S4 = sh_red[0][5] + sh_red[1][5] + sh_red[2][5] + sh_red[3][5];
        float C2 = sh_red[0][6] + sh_red[1][6] + sh_red[2][6] + sh_red[3][6];

        float ai = sh_ab[0];
        float bi = sh_ab[1];
        float di = ai * bi;
        float e  = di - 1.f;
        float e2 = e * e;

        // on_diag: Σ_j (d_j-1)^2 with j==i term replaced by ((d_i-1)^2 - 1)^2
        float on = R1 - e2 + (e2 - 1.f) * (e2 - 1.f);

        // off_diag:
        //   row i (p==i, q!=i): Σ_q (a_i b_q - 1)^4 - (d_i-1)^4
        //   rows p!=i, q!=p:    (A2 - a_i^2)*S2 - (C2 - d_i^2)
        float u  = ai;
        float u2 = u * u;
        float T4all = u2 * u2 * S4 - 4.f * u2 * u * S3 + 6.f * u2 * S2
                      - 4.f * u * S1 + (float)DD;
        float off = (T4all - e2 * e2) + (A2 - u2) * S2 - C2 + di * di;

        out[i] = on + LAMBDA_COEFF * off;
    }
}

extern "C" void kernel_launch(void* const* d_in, const int* in_sizes, int n_in,
                              void* d_out, int out_size, void* d_ws, size_t ws_size,
                              hipStream_t stream) {
    const float* z1 = (const float*)d_in[0];
    const float* z2 = (const float*)d_in[1];
    float* out   = (float*)d_out;
    float* stats = (float*)d_ws;  // 4*D floats = 16 KB

    bt_stats<<<2 * DD / 64, 256, 0, stream>>>(z1, z2, stats);
    bt_loss<<<BB, 256, 0, stream>>>(z1, z2, stats, out);
}